// Round 15
// baseline (1438.419 us; speedup 1.0000x reference)
//
#include <hip/hip_runtime.h>
#include <hip/hip_bf16.h>
#include <cstddef>

#define BB      32
#define TT_ALL  2048
#define EPROJS  1024
#define DUNITS  1024
#define ATT     512
#define CH      10
#define KS      201
#define FILT    100

// Output chunks (FP32), return order: c | w | h_new | c_new
#define OFF_C   0
#define OFF_W   (BB*EPROJS)
#define OFF_H   (OFF_W + BB*TT_ALL)
#define OFF_CN  (OFF_H + BB*ATT)

// ws layout (float offsets)
#define WS_CF    0
#define WS_V     512
#define WS_E     16896
#define WS_WF    82432

__device__ __forceinline__ float sigm(float x) { return 1.f / (1.f + expf(-x)); }

// ---------------------------------------------------------------------------
// K1: location conv -> relu -> max over T
__global__ __launch_bounds__(256) void k_conv(const float* __restrict__ att_prev,
                                              const float* __restrict__ W_conv,
                                              float* __restrict__ conv_feat) {
  const int b  = blockIdx.x / CH;
  const int ch = blockIdx.x % CH;
  __shared__ float sprev[TT_ALL + 2 * FILT];
  __shared__ float sw[KS];
  __shared__ float red[4];
  const int tid = threadIdx.x;
  for (int i = tid; i < TT_ALL + 2 * FILT; i += 256) {
    int t = i - FILT;
    sprev[i] = (t >= 0 && t < TT_ALL) ? att_prev[b * TT_ALL + t] : 0.f;
  }
  for (int i = tid; i < KS; i += 256) sw[i] = W_conv[ch * KS + i];
  __syncthreads();
  float m = 0.f;
  for (int t = tid; t < TT_ALL; t += 256) {
    float s = 0.f;
    for (int k = 0; k < KS; ++k) s = fmaf(sprev[t + k], sw[k], s);
    m = fmaxf(m, s);
  }
  for (int off = 32; off; off >>= 1) m = fmaxf(m, __shfl_xor(m, off, 64));
  if ((tid & 63) == 0) red[tid >> 6] = m;
  __syncthreads();
  if (tid == 0)
    conv_feat[b * CH + ch] = fmaxf(fmaxf(red[0], red[1]), fmaxf(red[2], red[3]));
}

// ---------------------------------------------------------------------------
// K2: gates -> LSTM -> h/c_new out (fp32); v = h_new + dec_z@W_dec
__global__ __launch_bounds__(256) void k_state(const float* __restrict__ conv_feat,
                                               const float* __restrict__ att_h,
                                               const float* __restrict__ att_c,
                                               const float* __restrict__ dec_z,
                                               const float* __restrict__ W_ih,
                                               const float* __restrict__ W_hh,
                                               const float* __restrict__ W_dec,
                                               float* __restrict__ v,
                                               float* __restrict__ out) {
  const int b = blockIdx.x;
  const int tid = threadIdx.x;
  __shared__ float sh[ATT];
  __shared__ float scf[CH];
  __shared__ float sz[DUNITS];
  __shared__ float sg[4 * ATT];
  if (tid < CH) scf[tid] = conv_feat[b * CH + tid];
  for (int i = tid; i < ATT; i += 256) sh[i] = att_h[b * ATT + i];
  for (int i = tid; i < DUNITS; i += 256) sz[i] = dec_z[b * DUNITS + i];
  __syncthreads();
  const int wid = tid >> 6, lane = tid & 63;
  for (int j = wid; j < 4 * ATT; j += 4) {
    const float* wr = &W_hh[(size_t)j * ATT];
    float acc = 0.f;
#pragma unroll
    for (int i = 0; i < ATT / 64; ++i) acc = fmaf(sh[lane + 64 * i], wr[lane + 64 * i], acc);
#pragma unroll
    for (int off = 32; off; off >>= 1) acc += __shfl_xor(acc, off, 64);
    if (lane == 0) {
      float g = 0.f;
      for (int c = 0; c < CH; ++c) g = fmaf(scf[c], W_ih[j * CH + c], g);
      sg[j] = acc + g;
    }
  }
  __syncthreads();
  for (int a = tid; a < ATT; a += 256) {
    const float ig = sigm(sg[a]);
    const float fg = sigm(sg[ATT + a]);
    const float gg = tanhf(sg[2 * ATT + a]);
    const float og = sigm(sg[3 * ATT + a]);
    const float cN = fg * att_c[b * ATT + a] + ig * gg;
    const float hN = og * tanhf(cN);
    out[OFF_H + b * ATT + a]  = hN;
    out[OFF_CN + b * ATT + a] = cN;
    float dt = 0.f;
    for (int d = 0; d < DUNITS; ++d) dt = fmaf(sz[d], W_dec[(size_t)d * ATT + a], dt);
    v[b * ATT + a] = hN + dt;
  }
}

// ---------------------------------------------------------------------------
// K3: e[b,t] = b_g + sum_a tanh(enc@W_enc + b_enc + v) * W_g  (documented)
#define STT 32
#define SKK 16
__global__ __launch_bounds__(256) void k_score(const float* __restrict__ enc,
                                               const float* __restrict__ W_enc,
                                               const float* __restrict__ b_enc,
                                               const float* __restrict__ W_g,
                                               const float* __restrict__ b_g,
                                               const float* __restrict__ v,
                                               const int* __restrict__ lens,
                                               float* __restrict__ e_out) {
  const int b = blockIdx.x >> 6;
  const int t0 = (blockIdx.x & 63) * STT;
  const int len = lens[b];
  if (t0 >= len) return;
  const int tid = threadIdx.x;

  __shared__ float sW[SKK][ATT];
  __shared__ float sE[SKK][STT];
  __shared__ float sva[ATT];
  __shared__ float swg[ATT];
  __shared__ float red[STT][33];

  for (int i = tid; i < ATT; i += 256) {
    sva[i] = v[b * ATT + i] + b_enc[i];
    swg[i] = W_g[i];
  }

  const int tr = tid & 7;
  const int ac = tid >> 3;
  float acc[4][16];
#pragma unroll
  for (int i = 0; i < 4; ++i)
#pragma unroll
    for (int j = 0; j < 16; ++j) acc[i][j] = 0.f;

  for (int kk = 0; kk < EPROJS; kk += SKK) {
    __syncthreads();
    if (tid < 128) {
      const int r = tid >> 2, c = tid & 3;
      const float4 ev = *reinterpret_cast<const float4*>(
          &enc[((size_t)b * TT_ALL + t0 + r) * EPROJS + kk + c * 4]);
      sE[c * 4 + 0][r] = ev.x; sE[c * 4 + 1][r] = ev.y;
      sE[c * 4 + 2][r] = ev.z; sE[c * 4 + 3][r] = ev.w;
    }
#pragma unroll
    for (int i = 0; i < 8; ++i) {
      const int f = tid + 256 * i;
      const int r = f >> 7, q = f & 127;
      *reinterpret_cast<float4*>(&sW[r][q * 4]) =
          *reinterpret_cast<const float4*>(&W_enc[(size_t)(kk + r) * ATT + q * 4]);
    }
    __syncthreads();
#pragma unroll
    for (int k = 0; k < SKK; ++k) {
      const float4 ev = *reinterpret_cast<const float4*>(&sE[k][tr * 4]);
      const float* wr = &sW[k][ac * 16];
      const float4 w0 = *reinterpret_cast<const float4*>(&wr[0]);
      const float4 w1 = *reinterpret_cast<const float4*>(&wr[4]);
      const float4 w2 = *reinterpret_cast<const float4*>(&wr[8]);
      const float4 w3 = *reinterpret_cast<const float4*>(&wr[12]);
      const float e4[4] = {ev.x, ev.y, ev.z, ev.w};
      const float wv[16] = {w0.x, w0.y, w0.z, w0.w, w1.x, w1.y, w1.z, w1.w,
                            w2.x, w2.y, w2.z, w2.w, w3.x, w3.y, w3.z, w3.w};
#pragma unroll
      for (int i = 0; i < 4; ++i)
#pragma unroll
        for (int j = 0; j < 16; ++j) acc[i][j] = fmaf(e4[i], wv[j], acc[i][j]);
    }
  }
  float part[4];
#pragma unroll
  for (int i = 0; i < 4; ++i) {
    float s = 0.f;
#pragma unroll
    for (int j = 0; j < 16; ++j) {
      const int a = ac * 16 + j;
      const float x = acc[i][j] + sva[a];
      s = fmaf(tanhf(x), swg[a], s);
    }
    part[i] = s;
  }
  __syncthreads();
#pragma unroll
  for (int i = 0; i < 4; ++i) red[tr * 4 + i][ac] = part[i];
  __syncthreads();
  if (tid < STT) {
    float s = b_g[0];
#pragma unroll
    for (int j = 0; j < 32; ++j) s += red[tid][j];
    e_out[b * TT_ALL + t0 + tid] = s;
  }
}

// ---------------------------------------------------------------------------
// K4: masked softmax(2*e), fp32 out
__global__ __launch_bounds__(256) void k_softmax(const float* __restrict__ e,
                                                 const int* __restrict__ lens,
                                                 float* __restrict__ wf,
                                                 float* __restrict__ out) {
  const int b = blockIdx.x, tid = threadIdx.x, len = lens[b];
  __shared__ float sbuf[4];
  float vals[8];
  float m = -1e30f;
#pragma unroll
  for (int i = 0; i < 8; ++i) {
    const int t = tid + i * 256;
    const float x = (t < len) ? e[b * TT_ALL + t] : -1e30f;
    vals[i] = x;
    m = fmaxf(m, x);
  }
  for (int off = 32; off; off >>= 1) m = fmaxf(m, __shfl_xor(m, off, 64));
  if ((tid & 63) == 0) sbuf[tid >> 6] = m;
  __syncthreads();
  m = fmaxf(fmaxf(sbuf[0], sbuf[1]), fmaxf(sbuf[2], sbuf[3]));
  __syncthreads();
  float s = 0.f;
#pragma unroll
  for (int i = 0; i < 8; ++i) {
    const int t = tid + i * 256;
    const float p = (t < len) ? expf(2.f * (vals[i] - m)) : 0.f;
    vals[i] = p;
    s += p;
  }
  for (int off = 32; off; off >>= 1) s += __shfl_xor(s, off, 64);
  if ((tid & 63) == 0) sbuf[tid >> 6] = s;
  __syncthreads();
  s = sbuf[0] + sbuf[1] + sbuf[2] + sbuf[3];
  const float inv = 1.f / s;
#pragma unroll
  for (int i = 0; i < 8; ++i) {
    const int t = tid + i * 256;
    const float wv = vals[i] * inv;
    wf[b * TT_ALL + t] = wv;
    out[OFF_W + b * TT_ALL + t] = wv;
  }
}

// ---------------------------------------------------------------------------
// K5: context, fp32 out
__global__ __launch_bounds__(256) void k_ctx_direct(const float* __restrict__ enc,
                                                    const float* __restrict__ wf,
                                                    const int* __restrict__ lens,
                                                    float* __restrict__ out) {
  const int b = blockIdx.x >> 2, et = blockIdx.x & 3;
  const int e = et * 256 + threadIdx.x;
  const int len = lens[b];
  float a0 = 0.f, a1 = 0.f, a2 = 0.f, a3 = 0.f;
  int t = 0;
  for (; t + 4 <= len; t += 4) {
    a0 = fmaf(wf[b * TT_ALL + t + 0], enc[((size_t)b * TT_ALL + t + 0) * EPROJS + e], a0);
    a1 = fmaf(wf[b * TT_ALL + t + 1], enc[((size_t)b * TT_ALL + t + 1) * EPROJS + e], a1);
    a2 = fmaf(wf[b * TT_ALL + t + 2], enc[((size_t)b * TT_ALL + t + 2) * EPROJS + e], a2);
    a3 = fmaf(wf[b * TT_ALL + t + 3], enc[((size_t)b * TT_ALL + t + 3) * EPROJS + e], a3);
  }
  for (; t < len; ++t)
    a0 = fmaf(wf[b * TT_ALL + t], enc[((size_t)b * TT_ALL + t) * EPROJS + e], a0);
  out[OFF_C + b * EPROJS + e] = a0 + a1 + a2 + a3;
}

// ---------------------------------------------------------------------------
extern "C" void kernel_launch(void* const* d_in, const int* in_sizes, int n_in,
                              void* d_out, int out_size, void* d_ws, size_t ws_size,
                              hipStream_t stream) {
  const float* enc      = (const float*)d_in[0];
  const int*   lens     = (const int*)d_in[1];
  const float* dec_z    = (const float*)d_in[2];
  const float* att_prev = (const float*)d_in[3];
  const float* att_h    = (const float*)d_in[4];
  const float* att_c    = (const float*)d_in[5];
  const float* W_enc    = (const float*)d_in[6];   // (EPROJS, ATT)
  const float* b_enc    = (const float*)d_in[7];
  const float* W_dec    = (const float*)d_in[8];   // (DUNITS, ATT)
  const float* W_conv   = (const float*)d_in[9];
  const float* W_ih     = (const float*)d_in[10];
  const float* W_hh     = (const float*)d_in[11];
  const float* W_g      = (const float*)d_in[12];
  const float* b_g      = (const float*)d_in[13];
  float* out = (float*)d_out;          // OUTPUTS ARE FP32 (R14 probe evidence)
  float* ws  = (float*)d_ws;

  float* cf   = ws + WS_CF;
  float* v    = ws + WS_V;
  float* e_s  = ws + WS_E;
  float* wf   = ws + WS_WF;

  k_conv      <<<BB * CH, 256, 0, stream>>>(att_prev, W_conv, cf);
  k_state     <<<BB, 256, 0, stream>>>(cf, att_h, att_c, dec_z, W_ih, W_hh, W_dec, v, out);
  k_score     <<<BB * (TT_ALL / STT), 256, 0, stream>>>(enc, W_enc, b_enc, W_g, b_g, v, lens, e_s);
  k_softmax   <<<BB, 256, 0, stream>>>(e_s, lens, wf, out);
  k_ctx_direct<<<BB * 4, 256, 0, stream>>>(enc, wf, lens, out);
}

// Round 16
// 672.691 us; speedup vs baseline: 2.1383x; 2.1383x over previous
//
#include <hip/hip_runtime.h>
#include <hip/hip_bf16.h>
#include <cstddef>

#define BB      32
#define TT_ALL  2048
#define EPROJS  1024
#define DUNITS  1024
#define ATT     512
#define CH      10
#define KS      201
#define FILT    100

// Output chunks (FP32): c | w | h_new | c_new
#define OFF_C   0
#define OFF_W   (BB*EPROJS)
#define OFF_H   (OFF_W + BB*TT_ALL)
#define OFF_CN  (OFF_H + BB*ATT)

// ws layout (float offsets)
#define WS_CF    0
#define WS_V     512
#define WS_E     16896
#define WS_WF    82432
#define WS_WT    147968                     // WT bf16 (512 x 1024) = 1 MB = 262144 f32 slots
#define WS_PART  (WS_WT + 262144)           // 32*8*1024 = 262144 floats

typedef __attribute__((ext_vector_type(8))) short short8;
typedef __attribute__((ext_vector_type(4))) float f32x4;

__device__ __forceinline__ float sigm(float x) { return 1.f / (1.f + expf(-x)); }
__device__ __forceinline__ unsigned short f2bf(float f) {
  unsigned u = __float_as_uint(f);
  return (unsigned short)((u + 0x7FFFu + ((u >> 16) & 1u)) >> 16);  // RNE
}

// ---------------------------------------------------------------------------
// K0: W_enc (E,A) fp32 -> WT (A,E) bf16, 32x32 tiles
__global__ __launch_bounds__(256) void k_wprep(const float* __restrict__ W,
                                               unsigned short* __restrict__ WT) {
  const int et = blockIdx.x >> 4;          // 32 tiles of e
  const int at = blockIdx.x & 15;          // 16 tiles of a
  const int e0 = et * 32, a0 = at * 32;
  __shared__ float st[32][36];
  const int tid = threadIdx.x;
  {
    const int r = tid >> 3, q = tid & 7;   // 32 rows x 8 float4
    const float4 v4 = *reinterpret_cast<const float4*>(&W[(size_t)(e0 + r) * ATT + a0 + q * 4]);
    st[r][q * 4 + 0] = v4.x; st[r][q * 4 + 1] = v4.y;
    st[r][q * 4 + 2] = v4.z; st[r][q * 4 + 3] = v4.w;
  }
  __syncthreads();
  {
    const int a = tid >> 3, q = tid & 7;   // 32 a-rows x 8 quads of e
    ushort4 h;
    h.x = f2bf(st[q * 4 + 0][a]); h.y = f2bf(st[q * 4 + 1][a]);
    h.z = f2bf(st[q * 4 + 2][a]); h.w = f2bf(st[q * 4 + 3][a]);
    *reinterpret_cast<ushort4*>(&WT[(size_t)(a0 + a) * EPROJS + e0 + q * 4]) = h;
  }
}

// ---------------------------------------------------------------------------
// K1: location conv -> relu -> max over T
__global__ __launch_bounds__(256) void k_conv(const float* __restrict__ att_prev,
                                              const float* __restrict__ W_conv,
                                              float* __restrict__ conv_feat) {
  const int b  = blockIdx.x / CH;
  const int ch = blockIdx.x % CH;
  __shared__ float sprev[TT_ALL + 2 * FILT];
  __shared__ float sw[KS];
  __shared__ float red[4];
  const int tid = threadIdx.x;
  for (int i = tid; i < TT_ALL + 2 * FILT; i += 256) {
    int t = i - FILT;
    sprev[i] = (t >= 0 && t < TT_ALL) ? att_prev[b * TT_ALL + t] : 0.f;
  }
  for (int i = tid; i < KS; i += 256) sw[i] = W_conv[ch * KS + i];
  __syncthreads();
  float m = 0.f;
  for (int t = tid; t < TT_ALL; t += 256) {
    float s = 0.f;
    for (int k = 0; k < KS; ++k) s = fmaf(sprev[t + k], sw[k], s);
    m = fmaxf(m, s);
  }
  for (int off = 32; off; off >>= 1) m = fmaxf(m, __shfl_xor(m, off, 64));
  if ((tid & 63) == 0) red[tid >> 6] = m;
  __syncthreads();
  if (tid == 0)
    conv_feat[b * CH + ch] = fmaxf(fmaxf(red[0], red[1]), fmaxf(red[2], red[3]));
}

// ---------------------------------------------------------------------------
// K2: gates -> LSTM -> h/c_new (fp32 out); v = h_new + dec_z@W_dec
__global__ __launch_bounds__(256) void k_state(const float* __restrict__ conv_feat,
                                               const float* __restrict__ att_h,
                                               const float* __restrict__ att_c,
                                               const float* __restrict__ dec_z,
                                               const float* __restrict__ W_ih,
                                               const float* __restrict__ W_hh,
                                               const float* __restrict__ W_dec,
                                               float* __restrict__ v,
                                               float* __restrict__ out) {
  const int b = blockIdx.x;
  const int tid = threadIdx.x;
  __shared__ float sh[ATT];
  __shared__ float scf[CH];
  __shared__ float sz[DUNITS];
  __shared__ float sg[4 * ATT];
  if (tid < CH) scf[tid] = conv_feat[b * CH + tid];
  for (int i = tid; i < ATT; i += 256) sh[i] = att_h[b * ATT + i];
  for (int i = tid; i < DUNITS; i += 256) sz[i] = dec_z[b * DUNITS + i];
  __syncthreads();
  const int wid = tid >> 6, lane = tid & 63;
  for (int j = wid; j < 4 * ATT; j += 4) {
    const float* wr = &W_hh[(size_t)j * ATT];
    float acc = 0.f;
#pragma unroll
    for (int i = 0; i < ATT / 64; ++i) acc = fmaf(sh[lane + 64 * i], wr[lane + 64 * i], acc);
#pragma unroll
    for (int off = 32; off; off >>= 1) acc += __shfl_xor(acc, off, 64);
    if (lane == 0) {
      float g = 0.f;
      for (int c = 0; c < CH; ++c) g = fmaf(scf[c], W_ih[j * CH + c], g);
      sg[j] = acc + g;
    }
  }
  __syncthreads();
  for (int a = tid; a < ATT; a += 256) {
    const float ig = sigm(sg[a]);
    const float fg = sigm(sg[ATT + a]);
    const float gg = tanhf(sg[2 * ATT + a]);
    const float og = sigm(sg[3 * ATT + a]);
    const float cN = fg * att_c[b * ATT + a] + ig * gg;
    const float hN = og * tanhf(cN);
    out[OFF_H + b * ATT + a]  = hN;
    out[OFF_CN + b * ATT + a] = cN;
    float dt = 0.f;
    for (int d = 0; d < DUNITS; ++d) dt = fmaf(sz[d], W_dec[(size_t)d * ATT + a], dt);
    v[b * ATT + a] = hN + dt;
  }
}

// ---------------------------------------------------------------------------
// K3: MFMA scoring. pre = enc @ W_enc via bf16 mfma_f32_16x16x32;
//     e = b_g + sum_a tanh(pre + v + b_enc)*W_g. Tile 64t x 512a, 4 waves.
#define MT 64
__global__ __launch_bounds__(256) void k_score_mfma(const float* __restrict__ enc,
                                                    const unsigned short* __restrict__ WT,
                                                    const float* __restrict__ b_enc,
                                                    const float* __restrict__ W_g,
                                                    const float* __restrict__ b_g,
                                                    const float* __restrict__ v,
                                                    const int* __restrict__ lens,
                                                    float* __restrict__ e_out) {
  const int b  = blockIdx.x >> 5;          // 32 t-tiles per b
  const int t0 = (blockIdx.x & 31) * MT;
  const int len = lens[b];
  if (t0 >= len) return;
  const int tid = threadIdx.x;
  const int lane = tid & 63, wid = tid >> 6;
  const int l15 = lane & 15, l4 = lane >> 4;
  const int a0w = wid * 128;

  __shared__ unsigned short sA[64][40];    // 64 t x 32 e (+pad), bf16
  __shared__ unsigned short sW[512][40];   // 512 a x 32 e (+pad), bf16
  __shared__ float sva[ATT];
  __shared__ float swg[ATT];
  __shared__ float red[64][5];

  for (int i = tid; i < ATT; i += 256) {
    sva[i] = v[b * ATT + i] + b_enc[i];
    swg[i] = W_g[i];
  }

  f32x4 acc[4][8];
#pragma unroll
  for (int m = 0; m < 4; ++m)
#pragma unroll
    for (int n = 0; n < 8; ++n) acc[m][n] = (f32x4){0.f, 0.f, 0.f, 0.f};

  for (int kk = 0; kk < EPROJS; kk += 32) {
    __syncthreads();
    // stage A: 64 rows x 32 e (fp32 -> bf16)
#pragma unroll
    for (int i = 0; i < 2; ++i) {
      const int c = tid + i * 256;
      const int row = c >> 3, q = c & 7;
      const float4 ev = *reinterpret_cast<const float4*>(
          &enc[((size_t)b * TT_ALL + t0 + row) * EPROJS + kk + q * 4]);
      ushort4 h;
      h.x = f2bf(ev.x); h.y = f2bf(ev.y); h.z = f2bf(ev.z); h.w = f2bf(ev.w);
      *reinterpret_cast<ushort4*>(&sA[row][q * 4]) = h;
    }
    // stage W: 512 rows x 32 e (bf16 copy from WT)
#pragma unroll
    for (int i = 0; i < 8; ++i) {
      const int c = tid + i * 256;
      const int row = c >> 2, part = c & 3;
      *reinterpret_cast<short8*>(&sW[row][part * 8]) =
          *reinterpret_cast<const short8*>(&WT[(size_t)row * EPROJS + kk + part * 8]);
    }
    __syncthreads();
    short8 af[4];
#pragma unroll
    for (int m = 0; m < 4; ++m)
      af[m] = *reinterpret_cast<const short8*>(&sA[16 * m + l15][l4 * 8]);
#pragma unroll
    for (int n = 0; n < 8; ++n) {
      const short8 bfr = *reinterpret_cast<const short8*>(&sW[a0w + 16 * n + l15][l4 * 8]);
#pragma unroll
      for (int m = 0; m < 4; ++m)
        acc[m][n] = __builtin_amdgcn_mfma_f32_16x16x32_bf16(af[m], bfr, acc[m][n], 0, 0, 0);
    }
  }

  // epilogue: tanh + W_g dot (D layout: col=lane&15, row=(lane>>4)*4+j)
  float rp[4][4];
#pragma unroll
  for (int m = 0; m < 4; ++m)
#pragma unroll
    for (int j = 0; j < 4; ++j) rp[m][j] = 0.f;
#pragma unroll
  for (int n = 0; n < 8; ++n) {
    const int a = a0w + 16 * n + l15;
    const float va = sva[a], wg = swg[a];
#pragma unroll
    for (int m = 0; m < 4; ++m)
#pragma unroll
      for (int j = 0; j < 4; ++j) {
        const float x = acc[m][n][j] + va;
        const float th = 1.f - 2.f / (__expf(2.f * x) + 1.f);
        rp[m][j] = fmaf(th, wg, rp[m][j]);
      }
  }
#pragma unroll
  for (int m = 0; m < 4; ++m)
#pragma unroll
    for (int j = 0; j < 4; ++j) {
      float s = rp[m][j];
      s += __shfl_xor(s, 1, 64);
      s += __shfl_xor(s, 2, 64);
      s += __shfl_xor(s, 4, 64);
      s += __shfl_xor(s, 8, 64);
      rp[m][j] = s;
    }
  __syncthreads();
  if (l15 == 0) {
#pragma unroll
    for (int m = 0; m < 4; ++m)
#pragma unroll
      for (int j = 0; j < 4; ++j)
        red[16 * m + l4 * 4 + j][wid] = rp[m][j];
  }
  __syncthreads();
  if (tid < 64) {
    const float s = b_g[0] + red[tid][0] + red[tid][1] + red[tid][2] + red[tid][3];
    e_out[b * TT_ALL + t0 + tid] = s;
  }
}

// ---------------------------------------------------------------------------
// K4: masked softmax(2*e), fp32 out
__global__ __launch_bounds__(256) void k_softmax(const float* __restrict__ e,
                                                 const int* __restrict__ lens,
                                                 float* __restrict__ wf,
                                                 float* __restrict__ out) {
  const int b = blockIdx.x, tid = threadIdx.x, len = lens[b];
  __shared__ float sbuf[4];
  float vals[8];
  float m = -1e30f;
#pragma unroll
  for (int i = 0; i < 8; ++i) {
    const int t = tid + i * 256;
    const float x = (t < len) ? e[b * TT_ALL + t] : -1e30f;
    vals[i] = x;
    m = fmaxf(m, x);
  }
  for (int off = 32; off; off >>= 1) m = fmaxf(m, __shfl_xor(m, off, 64));
  if ((tid & 63) == 0) sbuf[tid >> 6] = m;
  __syncthreads();
  m = fmaxf(fmaxf(sbuf[0], sbuf[1]), fmaxf(sbuf[2], sbuf[3]));
  __syncthreads();
  float s = 0.f;
#pragma unroll
  for (int i = 0; i < 8; ++i) {
    const int t = tid + i * 256;
    const float p = (t < len) ? expf(2.f * (vals[i] - m)) : 0.f;
    vals[i] = p;
    s += p;
  }
  for (int off = 32; off; off >>= 1) s += __shfl_xor(s, off, 64);
  if ((tid & 63) == 0) sbuf[tid >> 6] = s;
  __syncthreads();
  s = sbuf[0] + sbuf[1] + sbuf[2] + sbuf[3];
  const float inv = 1.f / s;
#pragma unroll
  for (int i = 0; i < 8; ++i) {
    const int t = tid + i * 256;
    const float wv = vals[i] * inv;
    wf[b * TT_ALL + t] = wv;
    out[OFF_W + b * TT_ALL + t] = wv;
  }
}

// ---------------------------------------------------------------------------
// K5/K6: context partials (1024 blocks) + combine, fp32 out
__global__ __launch_bounds__(256) void k_ctx(const float* __restrict__ enc,
                                             const float* __restrict__ wf,
                                             const int* __restrict__ lens,
                                             float* __restrict__ part) {
  const int blk = blockIdx.x;
  const int b  = blk >> 5;
  const int et = (blk >> 3) & 3;
  const int tc = blk & 7;
  const int tid = threadIdx.x;
  const int e = et * 256 + tid;
  const int len = lens[b];
  const int tbeg = tc * 256;
  const int tend = min(tbeg + 256, len);
  float a0 = 0.f, a1 = 0.f;
  int t = tbeg;
  for (; t + 2 <= tend; t += 2) {
    a0 = fmaf(wf[b * TT_ALL + t + 0], enc[((size_t)b * TT_ALL + t + 0) * EPROJS + e], a0);
    a1 = fmaf(wf[b * TT_ALL + t + 1], enc[((size_t)b * TT_ALL + t + 1) * EPROJS + e], a1);
  }
  for (; t < tend; ++t)
    a0 = fmaf(wf[b * TT_ALL + t], enc[((size_t)b * TT_ALL + t) * EPROJS + e], a0);
  part[((size_t)b * 8 + tc) * EPROJS + e] = a0 + a1;
}

__global__ __launch_bounds__(256) void k_comb(const float* __restrict__ part,
                                              float* __restrict__ out) {
  const int b = blockIdx.x >> 2, et = blockIdx.x & 3;
  const int e = et * 256 + threadIdx.x;
  float s = 0.f;
#pragma unroll
  for (int tc = 0; tc < 8; ++tc) s += part[((size_t)b * 8 + tc) * EPROJS + e];
  out[OFF_C + b * EPROJS + e] = s;
}

// ---------------------------------------------------------------------------
extern "C" void kernel_launch(void* const* d_in, const int* in_sizes, int n_in,
                              void* d_out, int out_size, void* d_ws, size_t ws_size,
                              hipStream_t stream) {
  const float* enc      = (const float*)d_in[0];
  const int*   lens     = (const int*)d_in[1];
  const float* dec_z    = (const float*)d_in[2];
  const float* att_prev = (const float*)d_in[3];
  const float* att_h    = (const float*)d_in[4];
  const float* att_c    = (const float*)d_in[5];
  const float* W_enc    = (const float*)d_in[6];   // (EPROJS, ATT)
  const float* b_enc    = (const float*)d_in[7];
  const float* W_dec    = (const float*)d_in[8];   // (DUNITS, ATT)
  const float* W_conv   = (const float*)d_in[9];
  const float* W_ih     = (const float*)d_in[10];
  const float* W_hh     = (const float*)d_in[11];
  const float* W_g      = (const float*)d_in[12];
  const float* b_g      = (const float*)d_in[13];
  float* out = (float*)d_out;
  float* ws  = (float*)d_ws;

  float* cf   = ws + WS_CF;
  float* v    = ws + WS_V;
  float* e_s  = ws + WS_E;
  float* wf   = ws + WS_WF;
  unsigned short* wt = (unsigned short*)(ws + WS_WT);
  float* part = ws + WS_PART;

  k_wprep     <<<512, 256, 0, stream>>>(W_enc, wt);
  k_conv      <<<BB * CH, 256, 0, stream>>>(att_prev, W_conv, cf);
  k_state     <<<BB, 256, 0, stream>>>(cf, att_h, att_c, dec_z, W_ih, W_hh, W_dec, v, out);
  k_score_mfma<<<BB * (TT_ALL / MT), 256, 0, stream>>>(enc, wt, b_enc, W_g, b_g, v, lens, e_s);
  k_softmax   <<<BB, 256, 0, stream>>>(e_s, lens, wf, out);
  k_ctx       <<<BB * 32, 256, 0, stream>>>(enc, wf, lens, part);
  k_comb      <<<BB * 4, 256, 0, stream>>>(part, out);
}

// Round 17
// 332.574 us; speedup vs baseline: 4.3251x; 2.0227x over previous
//
#include <hip/hip_runtime.h>
#include <hip/hip_bf16.h>
#include <cstddef>

#define BB      32
#define TT_ALL  2048
#define EPROJS  1024
#define DUNITS  1024
#define ATT     512
#define CH      10
#define KS      201
#define FILT    100

// Output chunks (FP32): c | w | h_new | c_new
#define OFF_C   0
#define OFF_W   (BB*EPROJS)
#define OFF_H   (OFF_W + BB*TT_ALL)
#define OFF_CN  (OFF_H + BB*ATT)

// ws layout (float offsets)
#define WS_CF    0
#define WS_V     512
#define WS_E     16896
#define WS_WF    82432
#define WS_WT    147968                      // WT bf16 (512x1024) = 262144 f32 slots
#define WS_PART  (WS_WT + 262144)            // ctx partials: 262144
#define WS_GP    (WS_PART + 262144)          // gates partials: 2*32*2048 = 131072
#define WS_DP    (WS_GP + 131072)            // dec partials: 2*32*512 = 32768

typedef __attribute__((ext_vector_type(8))) short short8;
typedef __attribute__((ext_vector_type(4))) float f32x4;

__device__ __forceinline__ float sigm(float x) { return 1.f / (1.f + expf(-x)); }
__device__ __forceinline__ unsigned short f2bf(float f) {
  unsigned u = __float_as_uint(f);
  return (unsigned short)((u + 0x7FFFu + ((u >> 16) & 1u)) >> 16);  // RNE
}

// ---------------------------------------------------------------------------
// K0: W_enc (E,A) fp32 -> WT (A,E) bf16
__global__ __launch_bounds__(256) void k_wprep(const float* __restrict__ W,
                                               unsigned short* __restrict__ WT) {
  const int et = blockIdx.x >> 4;
  const int at = blockIdx.x & 15;
  const int e0 = et * 32, a0 = at * 32;
  __shared__ float st[32][36];
  const int tid = threadIdx.x;
  {
    const int r = tid >> 3, q = tid & 7;
    const float4 v4 = *reinterpret_cast<const float4*>(&W[(size_t)(e0 + r) * ATT + a0 + q * 4]);
    st[r][q * 4 + 0] = v4.x; st[r][q * 4 + 1] = v4.y;
    st[r][q * 4 + 2] = v4.z; st[r][q * 4 + 3] = v4.w;
  }
  __syncthreads();
  {
    const int a = tid >> 3, q = tid & 7;
    ushort4 h;
    h.x = f2bf(st[q * 4 + 0][a]); h.y = f2bf(st[q * 4 + 1][a]);
    h.z = f2bf(st[q * 4 + 2][a]); h.w = f2bf(st[q * 4 + 3][a]);
    *reinterpret_cast<ushort4*>(&WT[(size_t)(a0 + a) * EPROJS + e0 + q * 4]) = h;
  }
}

// ---------------------------------------------------------------------------
// K1: location conv -> relu -> max over T
__global__ __launch_bounds__(256) void k_conv(const float* __restrict__ att_prev,
                                              const float* __restrict__ W_conv,
                                              float* __restrict__ conv_feat) {
  const int b  = blockIdx.x / CH;
  const int ch = blockIdx.x % CH;
  __shared__ float sprev[TT_ALL + 2 * FILT];
  __shared__ float sw[KS];
  __shared__ float red[4];
  const int tid = threadIdx.x;
  for (int i = tid; i < TT_ALL + 2 * FILT; i += 256) {
    int t = i - FILT;
    sprev[i] = (t >= 0 && t < TT_ALL) ? att_prev[b * TT_ALL + t] : 0.f;
  }
  for (int i = tid; i < KS; i += 256) sw[i] = W_conv[ch * KS + i];
  __syncthreads();
  float m = 0.f;
  for (int t = tid; t < TT_ALL; t += 256) {
    float s = 0.f;
    for (int k = 0; k < KS; ++k) s = fmaf(sprev[t + k], sw[k], s);
    m = fmaxf(m, s);
  }
  for (int off = 32; off; off >>= 1) m = fmaxf(m, __shfl_xor(m, off, 64));
  if ((tid & 63) == 0) red[tid >> 6] = m;
  __syncthreads();
  if (tid == 0)
    conv_feat[b * CH + ch] = fmaxf(fmaxf(red[0], red[1]), fmaxf(red[2], red[3]));
}

// ---------------------------------------------------------------------------
// K2a: gates partial: gp[sp][b][j] = sum_{k in split} att_h[b][k]*W_hh[j][k]
// grid: 32 j-tiles x 2 k-splits; block: 64 j x 4 b-groups(8 b)
__global__ __launch_bounds__(256) void k_gates(const float* __restrict__ att_h,
                                               const float* __restrict__ W_hh,
                                               float* __restrict__ gp) {
  const int jt = blockIdx.x >> 1;
  const int sp = blockIdx.x & 1;
  const int j0 = jt * 64;
  const int k0 = sp * 256;
  const int tid = threadIdx.x;
  const int al = tid & 63, bg = tid >> 6;
  __shared__ float sW[64][65];   // padded: compute-read bank = (j+k)%32, 2-way free
  __shared__ float sH[32][64];
  float acc[8];
#pragma unroll
  for (int i = 0; i < 8; ++i) acc[i] = 0.f;
  for (int kc = 0; kc < 256; kc += 64) {
    __syncthreads();
#pragma unroll
    for (int i = 0; i < 4; ++i) {               // W tile 64x64 (scalar LDS stores: [65] rows unaligned for float4)
      const int f = tid + i * 256;
      const int r = f >> 4, q = f & 15;
      const float4 w4 = *reinterpret_cast<const float4*>(
          &W_hh[(size_t)(j0 + r) * ATT + k0 + kc + q * 4]);
      sW[r][q * 4 + 0] = w4.x; sW[r][q * 4 + 1] = w4.y;
      sW[r][q * 4 + 2] = w4.z; sW[r][q * 4 + 3] = w4.w;
    }
#pragma unroll
    for (int i = 0; i < 2; ++i) {               // att_h tile 32x64
      const int g = tid + i * 256;
      const int r = g >> 4, q = g & 15;
      *reinterpret_cast<float4*>(&sH[r][q * 4]) = *reinterpret_cast<const float4*>(
          &att_h[(size_t)r * ATT + k0 + kc + q * 4]);
    }
    __syncthreads();
#pragma unroll 16
    for (int k = 0; k < 64; ++k) {
      const float w = sW[al][k];
#pragma unroll
      for (int bb = 0; bb < 8; ++bb)
        acc[bb] = fmaf(w, sH[bg * 8 + bb][k], acc[bb]);   // sH: wave-broadcast
    }
  }
#pragma unroll
  for (int bb = 0; bb < 8; ++bb)
    gp[((size_t)(sp * 32 + bg * 8 + bb)) * (4 * ATT) + j0 + al] = acc[bb];
}

// ---------------------------------------------------------------------------
// K2b: dec partial: dp[sp][b][a] = sum_{d in split} dec_z[b][d]*W_dec[d][a]
// grid: 8 a-tiles x 2 d-splits; block: 64 a x 4 b-groups(8 b)
__global__ __launch_bounds__(256) void k_dec(const float* __restrict__ dec_z,
                                             const float* __restrict__ W_dec,
                                             float* __restrict__ dp) {
  const int at = blockIdx.x >> 1;
  const int sp = blockIdx.x & 1;
  const int a0 = at * 64;
  const int d0 = sp * 512;
  const int tid = threadIdx.x;
  const int al = tid & 63, bg = tid >> 6;
  __shared__ float sW[64][64];   // read sW[d][al]: bank = al%32, 2-way free
  __shared__ float sZ[32][64];
  float acc[8];
#pragma unroll
  for (int i = 0; i < 8; ++i) acc[i] = 0.f;
  for (int dc = 0; dc < 512; dc += 64) {
    __syncthreads();
#pragma unroll
    for (int i = 0; i < 4; ++i) {               // W_dec tile 64d x 64a
      const int f = tid + i * 256;
      const int r = f >> 4, q = f & 15;
      *reinterpret_cast<float4*>(&sW[r][q * 4]) = *reinterpret_cast<const float4*>(
          &W_dec[(size_t)(d0 + dc + r) * ATT + a0 + q * 4]);
    }
#pragma unroll
    for (int i = 0; i < 2; ++i) {               // z tile 32b x 64d
      const int g = tid + i * 256;
      const int r = g >> 4, q = g & 15;
      *reinterpret_cast<float4*>(&sZ[r][q * 4]) = *reinterpret_cast<const float4*>(
          &dec_z[(size_t)r * DUNITS + d0 + dc + q * 4]);
    }
    __syncthreads();
#pragma unroll 16
    for (int d = 0; d < 64; ++d) {
      const float w = sW[d][al];
#pragma unroll
      for (int bb = 0; bb < 8; ++bb)
        acc[bb] = fmaf(sZ[bg * 8 + bb][d], w, acc[bb]);
    }
  }
#pragma unroll
  for (int bb = 0; bb < 8; ++bb)
    dp[((size_t)(sp * 32 + bg * 8 + bb)) * ATT + a0 + al] = acc[bb];
}

// ---------------------------------------------------------------------------
// K2c: combine partials + W_ih*cf, LSTM cell, v = h_new + dec_t. One block per b.
__global__ __launch_bounds__(256) void k_lstm_v(const float* __restrict__ gp,
                                                const float* __restrict__ dp,
                                                const float* __restrict__ conv_feat,
                                                const float* __restrict__ W_ih,
                                                const float* __restrict__ att_c,
                                                float* __restrict__ v,
                                                float* __restrict__ out) {
  const int b = blockIdx.x, tid = threadIdx.x;
  __shared__ float scf[CH];
  if (tid < CH) scf[tid] = conv_feat[b * CH + tid];
  __syncthreads();
  for (int a = tid; a < ATT; a += 256) {
    float g4[4];
#pragma unroll
    for (int q = 0; q < 4; ++q) {
      const int j = q * ATT + a;
      float g = gp[(size_t)b * (4 * ATT) + j] + gp[(size_t)(32 + b) * (4 * ATT) + j];
#pragma unroll
      for (int c = 0; c < CH; ++c) g = fmaf(scf[c], W_ih[(size_t)j * CH + c], g);
      g4[q] = g;
    }
    const float ig = sigm(g4[0]);
    const float fg = sigm(g4[1]);
    const float gg = tanhf(g4[2]);
    const float og = sigm(g4[3]);
    const float cN = fg * att_c[b * ATT + a] + ig * gg;
    const float hN = og * tanhf(cN);
    out[OFF_H + b * ATT + a]  = hN;
    out[OFF_CN + b * ATT + a] = cN;
    v[b * ATT + a] = hN + dp[(size_t)b * ATT + a] + dp[(size_t)(32 + b) * ATT + a];
  }
}

// ---------------------------------------------------------------------------
// K3: MFMA scoring (64t x 512a tile, 4 waves, bf16 16x16x32)
#define MT 64
__global__ __launch_bounds__(256) void k_score_mfma(const float* __restrict__ enc,
                                                    const unsigned short* __restrict__ WT,
                                                    const float* __restrict__ b_enc,
                                                    const float* __restrict__ W_g,
                                                    const float* __restrict__ b_g,
                                                    const float* __restrict__ v,
                                                    const int* __restrict__ lens,
                                                    float* __restrict__ e_out) {
  const int b  = blockIdx.x >> 5;
  const int t0 = (blockIdx.x & 31) * MT;
  const int len = lens[b];
  if (t0 >= len) return;
  const int tid = threadIdx.x;
  const int lane = tid & 63, wid = tid >> 6;
  const int l15 = lane & 15, l4 = lane >> 4;
  const int a0w = wid * 128;

  __shared__ unsigned short sA[64][40];
  __shared__ unsigned short sW[512][40];
  __shared__ float sva[ATT];
  __shared__ float swg[ATT];
  __shared__ float red[64][5];

  for (int i = tid; i < ATT; i += 256) {
    sva[i] = v[b * ATT + i] + b_enc[i];
    swg[i] = W_g[i];
  }

  f32x4 acc[4][8];
#pragma unroll
  for (int m = 0; m < 4; ++m)
#pragma unroll
    for (int n = 0; n < 8; ++n) acc[m][n] = (f32x4){0.f, 0.f, 0.f, 0.f};

  for (int kk = 0; kk < EPROJS; kk += 32) {
    __syncthreads();
#pragma unroll
    for (int i = 0; i < 2; ++i) {
      const int c = tid + i * 256;
      const int row = c >> 3, q = c & 7;
      const float4 ev = *reinterpret_cast<const float4*>(
          &enc[((size_t)b * TT_ALL + t0 + row) * EPROJS + kk + q * 4]);
      ushort4 h;
      h.x = f2bf(ev.x); h.y = f2bf(ev.y); h.z = f2bf(ev.z); h.w = f2bf(ev.w);
      *reinterpret_cast<ushort4*>(&sA[row][q * 4]) = h;
    }
#pragma unroll
    for (int i = 0; i < 8; ++i) {
      const int c = tid + i * 256;
      const int row = c >> 2, part = c & 3;
      *reinterpret_cast<short8*>(&sW[row][part * 8]) =
          *reinterpret_cast<const short8*>(&WT[(size_t)row * EPROJS + kk + part * 8]);
    }
    __syncthreads();
    short8 af[4];
#pragma unroll
    for (int m = 0; m < 4; ++m)
      af[m] = *reinterpret_cast<const short8*>(&sA[16 * m + l15][l4 * 8]);
#pragma unroll
    for (int n = 0; n < 8; ++n) {
      const short8 bfr = *reinterpret_cast<const short8*>(&sW[a0w + 16 * n + l15][l4 * 8]);
#pragma unroll
      for (int m = 0; m < 4; ++m)
        acc[m][n] = __builtin_amdgcn_mfma_f32_16x16x32_bf16(af[m], bfr, acc[m][n], 0, 0, 0);
    }
  }

  float rp[4][4];
#pragma unroll
  for (int m = 0; m < 4; ++m)
#pragma unroll
    for (int j = 0; j < 4; ++j) rp[m][j] = 0.f;
#pragma unroll
  for (int n = 0; n < 8; ++n) {
    const int a = a0w + 16 * n + l15;
    const float va = sva[a], wg = swg[a];
#pragma unroll
    for (int m = 0; m < 4; ++m)
#pragma unroll
      for (int j = 0; j < 4; ++j) {
        const float x = acc[m][n][j] + va;
        const float th = 1.f - 2.f / (__expf(2.f * x) + 1.f);
        rp[m][j] = fmaf(th, wg, rp[m][j]);
      }
  }
#pragma unroll
  for (int m = 0; m < 4; ++m)
#pragma unroll
    for (int j = 0; j < 4; ++j) {
      float s = rp[m][j];
      s += __shfl_xor(s, 1, 64);
      s += __shfl_xor(s, 2, 64);
      s += __shfl_xor(s, 4, 64);
      s += __shfl_xor(s, 8, 64);
      rp[m][j] = s;
    }
  __syncthreads();
  if (l15 == 0) {
#pragma unroll
    for (int m = 0; m < 4; ++m)
#pragma unroll
      for (int j = 0; j < 4; ++j)
        red[16 * m + l4 * 4 + j][wid] = rp[m][j];
  }
  __syncthreads();
  if (tid < 64) {
    const float s = b_g[0] + red[tid][0] + red[tid][1] + red[tid][2] + red[tid][3];
    e_out[b * TT_ALL + t0 + tid] = s;
  }
}

// ---------------------------------------------------------------------------
// K4: masked softmax(2*e)
__global__ __launch_bounds__(256) void k_softmax(const float* __restrict__ e,
                                                 const int* __restrict__ lens,
                                                 float* __restrict__ wf,
                                                 float* __restrict__ out) {
  const int b = blockIdx.x, tid = threadIdx.x, len = lens[b];
  __shared__ float sbuf[4];
  float vals[8];
  float m = -1e30f;
#pragma unroll
  for (int i = 0; i < 8; ++i) {
    const int t = tid + i * 256;
    const float x = (t < len) ? e[b * TT_ALL + t] : -1e30f;
    vals[i] = x;
    m = fmaxf(m, x);
  }
  for (int off = 32; off; off >>= 1) m = fmaxf(m, __shfl_xor(m, off, 64));
  if ((tid & 63) == 0) sbuf[tid >> 6] = m;
  __syncthreads();
  m = fmaxf(fmaxf(sbuf[0], sbuf[1]), fmaxf(sbuf[2], sbuf[3]));
  __syncthreads();
  float s = 0.f;
#pragma unroll
  for (int i = 0; i < 8; ++i) {
    const int t = tid + i * 256;
    const float p = (t < len) ? expf(2.f * (vals[i] - m)) : 0.f;
    vals[i] = p;
    s += p;
  }
  for (int off = 32; off; off >>= 1) s += __shfl_xor(s, off, 64);
  if ((tid & 63) == 0) sbuf[tid >> 6] = s;
  __syncthreads();
  s = sbuf[0] + sbuf[1] + sbuf[2] + sbuf[3];
  const float inv = 1.f / s;
#pragma unroll
  for (int i = 0; i < 8; ++i) {
    const int t = tid + i * 256;
    const float wv = vals[i] * inv;
    wf[b * TT_ALL + t] = wv;
    out[OFF_W + b * TT_ALL + t] = wv;
  }
}

// ---------------------------------------------------------------------------
// K5/K6: context partials + combine
__global__ __launch_bounds__(256) void k_ctx(const float* __restrict__ enc,
                                             const float* __restrict__ wf,
                                             const int* __restrict__ lens,
                                             float* __restrict__ part) {
  const int blk = blockIdx.x;
  const int b  = blk >> 5;
  const int et = (blk >> 3) & 3;
  const int tc = blk & 7;
  const int tid = threadIdx.x;
  const int e = et * 256 + tid;
  const int len = lens[b];
  const int tbeg = tc * 256;
  const int tend = min(tbeg + 256, len);
  float a0 = 0.f, a1 = 0.f;
  int t = tbeg;
  for (; t + 2 <= tend; t += 2) {
    a0 = fmaf(wf[b * TT_ALL + t + 0], enc[((size_t)b * TT_ALL + t + 0) * EPROJS + e], a0);
    a1 = fmaf(wf[b * TT_ALL + t + 1], enc[((size_t)b * TT_ALL + t + 1) * EPROJS + e], a1);
  }
  for (; t < tend; ++t)
    a0 = fmaf(wf[b * TT_ALL + t], enc[((size_t)b * TT_ALL + t) * EPROJS + e], a0);
  part[((size_t)b * 8 + tc) * EPROJS + e] = a0 + a1;
}

__global__ __launch_bounds__(256) void k_comb(const float* __restrict__ part,
                                              float* __restrict__ out) {
  const int b = blockIdx.x >> 2, et = blockIdx.x & 3;
  const int e = et * 256 + threadIdx.x;
  float s = 0.f;
#pragma unroll
  for (int tc = 0; tc < 8; ++tc) s += part[((size_t)b * 8 + tc) * EPROJS + e];
  out[OFF_C + b * EPROJS + e] = s;
}

// ---------------------------------------------------------------------------
extern "C" void kernel_launch(void* const* d_in, const int* in_sizes, int n_in,
                              void* d_out, int out_size, void* d_ws, size_t ws_size,
                              hipStream_t stream) {
  const float* enc      = (const float*)d_in[0];
  const int*   lens     = (const int*)d_in[1];
  const float* dec_z    = (const float*)d_in[2];
  const float* att_prev = (const float*)d_in[3];
  const float* att_h    = (const float*)d_in[4];
  const float* att_c    = (const float*)d_in[5];
  const float* W_enc    = (const float*)d_in[6];
  const float* b_enc    = (const float*)d_in[7];
  const float* W_dec    = (const float*)d_in[8];
  const float* W_conv   = (const float*)d_in[9];
  const float* W_ih     = (const float*)d_in[10];
  const float* W_hh     = (const float*)d_in[11];
  const float* W_g      = (const float*)d_in[12];
  const float* b_g      = (const float*)d_in[13];
  float* out = (float*)d_out;
  float* ws  = (float*)d_ws;

  float* cf   = ws + WS_CF;
  float* v    = ws + WS_V;
  float* e_s  = ws + WS_E;
  float* wf   = ws + WS_WF;
  unsigned short* wt = (unsigned short*)(ws + WS_WT);
  float* part = ws + WS_PART;
  float* gp   = ws + WS_GP;
  float* dp   = ws + WS_DP;

  k_wprep     <<<512, 256, 0, stream>>>(W_enc, wt);
  k_conv      <<<BB * CH, 256, 0, stream>>>(att_prev, W_conv, cf);
  k_gates     <<<64, 256, 0, stream>>>(att_h, W_hh, gp);
  k_dec       <<<16, 256, 0, stream>>>(dec_z, W_dec, dp);
  k_lstm_v    <<<BB, 256, 0, stream>>>(gp, dp, cf, W_ih, att_c, v, out);
  k_score_mfma<<<BB * (TT_ALL / MT), 256, 0, stream>>>(enc, wt, b_enc, W_g, b_g, v, lens, e_s);
  k_softmax   <<<BB, 256, 0, stream>>>(e_s, lens, wf, out);
  k_ctx       <<<BB * 32, 256, 0, stream>>>(enc, wf, lens, part);
  k_comb      <<<BB * 4, 256, 0, stream>>>(part, out);
}

// Round 18
// 236.788 us; speedup vs baseline: 6.0747x; 1.4045x over previous
//
#include <hip/hip_runtime.h>
#include <hip/hip_bf16.h>
#include <cstddef>

#define BB      32
#define TT_ALL  2048
#define EPROJS  1024
#define DUNITS  1024
#define ATT     512
#define CH      10
#define KS      201
#define FILT    100

// Output chunks (FP32): c | w | h_new | c_new
#define OFF_C   0
#define OFF_W   (BB*EPROJS)
#define OFF_H   (OFF_W + BB*TT_ALL)
#define OFF_CN  (OFF_H + BB*ATT)

// ws layout (float offsets)
#define WS_CF    0
#define WS_V     512
#define WS_E     16896
#define WS_WF    82432
#define WS_WT    147968
#define WS_PART  (WS_WT + 262144)
#define WS_GP    (WS_PART + 262144)
#define WS_DP    (WS_GP + 131072)

typedef __attribute__((ext_vector_type(8))) short short8;
typedef __attribute__((ext_vector_type(4))) float f32x4;

__device__ __forceinline__ float sigm(float x) { return 1.f / (1.f + expf(-x)); }
__device__ __forceinline__ unsigned short f2bf(float f) {
  unsigned u = __float_as_uint(f);
  return (unsigned short)((u + 0x7FFFu + ((u >> 16) & 1u)) >> 16);  // RNE
}
__device__ __forceinline__ ushort2 f2bf2(float a, float b) {
  __hip_bfloat162 h = __float22bfloat162_rn(float2{a, b});  // packed cvt
  return *reinterpret_cast<ushort2*>(&h);
}

// ---------------------------------------------------------------------------
// K0: W_enc (E,A) fp32 -> WT (A,E) bf16
__global__ __launch_bounds__(256) void k_wprep(const float* __restrict__ W,
                                               unsigned short* __restrict__ WT) {
  const int et = blockIdx.x >> 4;
  const int at = blockIdx.x & 15;
  const int e0 = et * 32, a0 = at * 32;
  __shared__ float st[32][36];
  const int tid = threadIdx.x;
  {
    const int r = tid >> 3, q = tid & 7;
    const float4 v4 = *reinterpret_cast<const float4*>(&W[(size_t)(e0 + r) * ATT + a0 + q * 4]);
    st[r][q * 4 + 0] = v4.x; st[r][q * 4 + 1] = v4.y;
    st[r][q * 4 + 2] = v4.z; st[r][q * 4 + 3] = v4.w;
  }
  __syncthreads();
  {
    const int a = tid >> 3, q = tid & 7;
    ushort4 h;
    h.x = f2bf(st[q * 4 + 0][a]); h.y = f2bf(st[q * 4 + 1][a]);
    h.z = f2bf(st[q * 4 + 2][a]); h.w = f2bf(st[q * 4 + 3][a]);
    *reinterpret_cast<ushort4*>(&WT[(size_t)(a0 + a) * EPROJS + e0 + q * 4]) = h;
  }
}

// ---------------------------------------------------------------------------
// K1: location conv -> relu -> max over T
__global__ __launch_bounds__(256) void k_conv(const float* __restrict__ att_prev,
                                              const float* __restrict__ W_conv,
                                              float* __restrict__ conv_feat) {
  const int b  = blockIdx.x / CH;
  const int ch = blockIdx.x % CH;
  __shared__ float sprev[TT_ALL + 2 * FILT];
  __shared__ float sw[KS];
  __shared__ float red[4];
  const int tid = threadIdx.x;
  for (int i = tid; i < TT_ALL + 2 * FILT; i += 256) {
    int t = i - FILT;
    sprev[i] = (t >= 0 && t < TT_ALL) ? att_prev[b * TT_ALL + t] : 0.f;
  }
  for (int i = tid; i < KS; i += 256) sw[i] = W_conv[ch * KS + i];
  __syncthreads();
  float m = 0.f;
  for (int t = tid; t < TT_ALL; t += 256) {
    float s = 0.f;
    for (int k = 0; k < KS; ++k) s = fmaf(sprev[t + k], sw[k], s);
    m = fmaxf(m, s);
  }
  for (int off = 32; off; off >>= 1) m = fmaxf(m, __shfl_xor(m, off, 64));
  if ((tid & 63) == 0) red[tid >> 6] = m;
  __syncthreads();
  if (tid == 0)
    conv_feat[b * CH + ch] = fmaxf(fmaxf(red[0], red[1]), fmaxf(red[2], red[3]));
}

// ---------------------------------------------------------------------------
// K2a: gates partial
__global__ __launch_bounds__(256) void k_gates(const float* __restrict__ att_h,
                                               const float* __restrict__ W_hh,
                                               float* __restrict__ gp) {
  const int jt = blockIdx.x >> 1;
  const int sp = blockIdx.x & 1;
  const int j0 = jt * 64;
  const int k0 = sp * 256;
  const int tid = threadIdx.x;
  const int al = tid & 63, bg = tid >> 6;
  __shared__ float sW[64][65];
  __shared__ float sH[32][64];
  float acc[8];
#pragma unroll
  for (int i = 0; i < 8; ++i) acc[i] = 0.f;
  for (int kc = 0; kc < 256; kc += 64) {
    __syncthreads();
#pragma unroll
    for (int i = 0; i < 4; ++i) {
      const int f = tid + i * 256;
      const int r = f >> 4, q = f & 15;
      const float4 w4 = *reinterpret_cast<const float4*>(
          &W_hh[(size_t)(j0 + r) * ATT + k0 + kc + q * 4]);
      sW[r][q * 4 + 0] = w4.x; sW[r][q * 4 + 1] = w4.y;
      sW[r][q * 4 + 2] = w4.z; sW[r][q * 4 + 3] = w4.w;
    }
#pragma unroll
    for (int i = 0; i < 2; ++i) {
      const int g = tid + i * 256;
      const int r = g >> 4, q = g & 15;
      *reinterpret_cast<float4*>(&sH[r][q * 4]) = *reinterpret_cast<const float4*>(
          &att_h[(size_t)r * ATT + k0 + kc + q * 4]);
    }
    __syncthreads();
#pragma unroll 16
    for (int k = 0; k < 64; ++k) {
      const float w = sW[al][k];
#pragma unroll
      for (int bb = 0; bb < 8; ++bb)
        acc[bb] = fmaf(w, sH[bg * 8 + bb][k], acc[bb]);
    }
  }
#pragma unroll
  for (int bb = 0; bb < 8; ++bb)
    gp[((size_t)(sp * 32 + bg * 8 + bb)) * (4 * ATT) + j0 + al] = acc[bb];
}

// ---------------------------------------------------------------------------
// K2b: dec partial
__global__ __launch_bounds__(256) void k_dec(const float* __restrict__ dec_z,
                                             const float* __restrict__ W_dec,
                                             float* __restrict__ dp) {
  const int at = blockIdx.x >> 1;
  const int sp = blockIdx.x & 1;
  const int a0 = at * 64;
  const int d0 = sp * 512;
  const int tid = threadIdx.x;
  const int al = tid & 63, bg = tid >> 6;
  __shared__ float sW[64][64];
  __shared__ float sZ[32][64];
  float acc[8];
#pragma unroll
  for (int i = 0; i < 8; ++i) acc[i] = 0.f;
  for (int dc = 0; dc < 512; dc += 64) {
    __syncthreads();
#pragma unroll
    for (int i = 0; i < 4; ++i) {
      const int f = tid + i * 256;
      const int r = f >> 4, q = f & 15;
      *reinterpret_cast<float4*>(&sW[r][q * 4]) = *reinterpret_cast<const float4*>(
          &W_dec[(size_t)(d0 + dc + r) * ATT + a0 + q * 4]);
    }
#pragma unroll
    for (int i = 0; i < 2; ++i) {
      const int g = tid + i * 256;
      const int r = g >> 4, q = g & 15;
      *reinterpret_cast<float4*>(&sZ[r][q * 4]) = *reinterpret_cast<const float4*>(
          &dec_z[(size_t)r * DUNITS + d0 + dc + q * 4]);
    }
    __syncthreads();
#pragma unroll 16
    for (int d = 0; d < 64; ++d) {
      const float w = sW[d][al];
#pragma unroll
      for (int bb = 0; bb < 8; ++bb)
        acc[bb] = fmaf(sZ[bg * 8 + bb][d], w, acc[bb]);
    }
  }
#pragma unroll
  for (int bb = 0; bb < 8; ++bb)
    dp[((size_t)(sp * 32 + bg * 8 + bb)) * ATT + a0 + al] = acc[bb];
}

// ---------------------------------------------------------------------------
// K2c: combine + LSTM + v
__global__ __launch_bounds__(256) void k_lstm_v(const float* __restrict__ gp,
                                                const float* __restrict__ dp,
                                                const float* __restrict__ conv_feat,
                                                const float* __restrict__ W_ih,
                                                const float* __restrict__ att_c,
                                                float* __restrict__ v,
                                                float* __restrict__ out) {
  const int b = blockIdx.x, tid = threadIdx.x;
  __shared__ float scf[CH];
  if (tid < CH) scf[tid] = conv_feat[b * CH + tid];
  __syncthreads();
  for (int a = tid; a < ATT; a += 256) {
    float g4[4];
#pragma unroll
    for (int q = 0; q < 4; ++q) {
      const int j = q * ATT + a;
      float g = gp[(size_t)b * (4 * ATT) + j] + gp[(size_t)(32 + b) * (4 * ATT) + j];
#pragma unroll
      for (int c = 0; c < CH; ++c) g = fmaf(scf[c], W_ih[(size_t)j * CH + c], g);
      g4[q] = g;
    }
    const float ig = sigm(g4[0]);
    const float fg = sigm(g4[1]);
    const float gg = tanhf(g4[2]);
    const float og = sigm(g4[3]);
    const float cN = fg * att_c[b * ATT + a] + ig * gg;
    const float hN = og * tanhf(cN);
    out[OFF_H + b * ATT + a]  = hN;
    out[OFF_CN + b * ATT + a] = cN;
    v[b * ATT + a] = hN + dp[(size_t)b * ATT + a] + dp[(size_t)(32 + b) * ATT + a];
  }
}

// ---------------------------------------------------------------------------
// K3 v2: MFMA scoring. M=128t x N=512a per block, 8 waves (2m x 4n),
// wave=64x128, K-step 32, 2-phase reg-staged pipeline.
#define MT2 128
__global__ __launch_bounds__(512) void k_score_mfma(const float* __restrict__ enc,
                                                    const unsigned short* __restrict__ WT,
                                                    const float* __restrict__ b_enc,
                                                    const float* __restrict__ W_g,
                                                    const float* __restrict__ b_g,
                                                    const float* __restrict__ v,
                                                    const int* __restrict__ lens,
                                                    float* __restrict__ e_out) {
  const int b  = blockIdx.x >> 4;
  const int t0 = (blockIdx.x & 15) * MT2;
  const int len = lens[b];
  if (t0 >= len) return;
  const int tid = threadIdx.x;
  const int lane = tid & 63, wid = tid >> 6;
  const int l15 = lane & 15, l4 = lane >> 4;
  const int wm = wid >> 2, wn = wid & 3;
  const int a0w = wn * 128;

  __shared__ unsigned short sA[128][40];   // 128 t x 32 e (+pad)
  __shared__ unsigned short sW[512][40];   // 512 a x 32 e (+pad)
  __shared__ float red[128][5];

  const size_t encBase = ((size_t)b * TT_ALL + t0) * EPROJS;

  // staging indices (512 threads)
  const int cA0 = tid, cA1 = tid + 512;            // float4 units, 1024 total
  const int rA0 = cA0 >> 3, qA0 = cA0 & 7;
  const int rA1 = cA1 >> 3, qA1 = cA1 & 7;
  int rW[4], pW[4];
#pragma unroll
  for (int i = 0; i < 4; ++i) {
    const int c = tid + i * 512;
    rW[i] = c >> 2; pW[i] = c & 3;
  }

  float4 ar[2];
  short8 wr[4];
  // prologue: issue k=0 loads
  ar[0] = *reinterpret_cast<const float4*>(&enc[encBase + (size_t)rA0 * EPROJS + qA0 * 4]);
  ar[1] = *reinterpret_cast<const float4*>(&enc[encBase + (size_t)rA1 * EPROJS + qA1 * 4]);
#pragma unroll
  for (int i = 0; i < 4; ++i)
    wr[i] = *reinterpret_cast<const short8*>(&WT[(size_t)rW[i] * EPROJS + pW[i] * 8]);

  f32x4 acc[4][8];
#pragma unroll
  for (int m = 0; m < 4; ++m)
#pragma unroll
    for (int n = 0; n < 8; ++n) acc[m][n] = (f32x4){0.f, 0.f, 0.f, 0.f};

  for (int kk = 0; kk < EPROJS; kk += 32) {
    // store phase (compiler waits on ar/wr as needed)
    {
      ushort2 h0 = f2bf2(ar[0].x, ar[0].y), h1 = f2bf2(ar[0].z, ar[0].w);
      ushort4 h; h.x = h0.x; h.y = h0.y; h.z = h1.x; h.w = h1.y;
      *reinterpret_cast<ushort4*>(&sA[rA0][qA0 * 4]) = h;
      h0 = f2bf2(ar[1].x, ar[1].y); h1 = f2bf2(ar[1].z, ar[1].w);
      h.x = h0.x; h.y = h0.y; h.z = h1.x; h.w = h1.y;
      *reinterpret_cast<ushort4*>(&sA[rA1][qA1 * 4]) = h;
    }
#pragma unroll
    for (int i = 0; i < 4; ++i)
      *reinterpret_cast<short8*>(&sW[rW[i]][pW[i] * 8]) = wr[i];
    __syncthreads();
    // issue next-tile loads (latency hides under MFMA below)
    if (kk + 32 < EPROJS) {
      const int kn = kk + 32;
      ar[0] = *reinterpret_cast<const float4*>(&enc[encBase + (size_t)rA0 * EPROJS + kn + qA0 * 4]);
      ar[1] = *reinterpret_cast<const float4*>(&enc[encBase + (size_t)rA1 * EPROJS + kn + qA1 * 4]);
#pragma unroll
      for (int i = 0; i < 4; ++i)
        wr[i] = *reinterpret_cast<const short8*>(&WT[(size_t)rW[i] * EPROJS + kn + pW[i] * 8]);
    }
    // compute phase
    short8 af[4];
#pragma unroll
    for (int m = 0; m < 4; ++m)
      af[m] = *reinterpret_cast<const short8*>(&sA[wm * 64 + 16 * m + l15][l4 * 8]);
#pragma unroll
    for (int n = 0; n < 8; ++n) {
      const short8 bfr = *reinterpret_cast<const short8*>(&sW[a0w + 16 * n + l15][l4 * 8]);
#pragma unroll
      for (int m = 0; m < 4; ++m)
        acc[m][n] = __builtin_amdgcn_mfma_f32_16x16x32_bf16(af[m], bfr, acc[m][n], 0, 0, 0);
    }
    __syncthreads();
  }

  // epilogue: tanh + W_g contraction (D: col=l15 -> a, row=(l4)*4+j within frag)
  float rp[4][4];
#pragma unroll
  for (int m = 0; m < 4; ++m)
#pragma unroll
    for (int j = 0; j < 4; ++j) rp[m][j] = 0.f;
#pragma unroll
  for (int n = 0; n < 8; ++n) {
    const int a = a0w + 16 * n + l15;
    const float va = v[b * ATT + a] + b_enc[a];
    const float wg = W_g[a];
#pragma unroll
    for (int m = 0; m < 4; ++m)
#pragma unroll
      for (int j = 0; j < 4; ++j) {
        const float x = acc[m][n][j] + va;
        const float th = 1.f - 2.f / (__expf(2.f * x) + 1.f);
        rp[m][j] = fmaf(th, wg, rp[m][j]);
      }
  }
#pragma unroll
  for (int m = 0; m < 4; ++m)
#pragma unroll
    for (int j = 0; j < 4; ++j) {
      float s = rp[m][j];
      s += __shfl_xor(s, 1, 64);
      s += __shfl_xor(s, 2, 64);
      s += __shfl_xor(s, 4, 64);
      s += __shfl_xor(s, 8, 64);
      rp[m][j] = s;
    }
  if (l15 == 0) {
#pragma unroll
    for (int m = 0; m < 4; ++m)
#pragma unroll
      for (int j = 0; j < 4; ++j)
        red[wm * 64 + m * 16 + l4 * 4 + j][wn] = rp[m][j];
  }
  __syncthreads();
  if (tid < MT2) {
    const float s = b_g[0] + red[tid][0] + red[tid][1] + red[tid][2] + red[tid][3];
    e_out[b * TT_ALL + t0 + tid] = s;
  }
}

// ---------------------------------------------------------------------------
// K4: masked softmax(2*e)
__global__ __launch_bounds__(256) void k_softmax(const float* __restrict__ e,
                                                 const int* __restrict__ lens,
                                                 float* __restrict__ wf,
                                                 float* __restrict__ out) {
  const int b = blockIdx.x, tid = threadIdx.x, len = lens[b];
  __shared__ float sbuf[4];
  float vals[8];
  float m = -1e30f;
#pragma unroll
  for (int i = 0; i < 8; ++i) {
    const int t = tid + i * 256;
    const float x = (t < len) ? e[b * TT_ALL + t] : -1e30f;
    vals[i] = x;
    m = fmaxf(m, x);
  }
  for (int off = 32; off; off >>= 1) m = fmaxf(m, __shfl_xor(m, off, 64));
  if ((tid & 63) == 0) sbuf[tid >> 6] = m;
  __syncthreads();
  m = fmaxf(fmaxf(sbuf[0], sbuf[1]), fmaxf(sbuf[2], sbuf[3]));
  __syncthreads();
  float s = 0.f;
#pragma unroll
  for (int i = 0; i < 8; ++i) {
    const int t = tid + i * 256;
    const float p = (t < len) ? expf(2.f * (vals[i] - m)) : 0.f;
    vals[i] = p;
    s += p;
  }
  for (int off = 32; off; off >>= 1) s += __shfl_xor(s, off, 64);
  if ((tid & 63) == 0) sbuf[tid >> 6] = s;
  __syncthreads();
  s = sbuf[0] + sbuf[1] + sbuf[2] + sbuf[3];
  const float inv = 1.f / s;
#pragma unroll
  for (int i = 0; i < 8; ++i) {
    const int t = tid + i * 256;
    const float wv = vals[i] * inv;
    wf[b * TT_ALL + t] = wv;
    out[OFF_W + b * TT_ALL + t] = wv;
  }
}

// ---------------------------------------------------------------------------
// K5/K6: context partials + combine
__global__ __launch_bounds__(256) void k_ctx(const float* __restrict__ enc,
                                             const float* __restrict__ wf,
                                             const int* __restrict__ lens,
                                             float* __restrict__ part) {
  const int blk = blockIdx.x;
  const int b  = blk >> 5;
  const int et = (blk >> 3) & 3;
  const int tc = blk & 7;
  const int tid = threadIdx.x;
  const int e = et * 256 + tid;
  const int len = lens[b];
  const int tbeg = tc * 256;
  const int tend = min(tbeg + 256, len);
  float a0 = 0.f, a1 = 0.f;
  int t = tbeg;
  for (; t + 2 <= tend; t += 2) {
    a0 = fmaf(wf[b * TT_ALL + t + 0], enc[((size_t)b * TT_ALL + t + 0) * EPROJS + e], a0);
    a1 = fmaf(wf[b * TT_ALL + t + 1], enc[((size_t)b * TT_ALL + t + 1) * EPROJS + e], a1);
  }
  for (; t < tend; ++t)
    a0 = fmaf(wf[b * TT_ALL + t], enc[((size_t)b * TT_ALL + t) * EPROJS + e], a0);
  part[((size_t)b * 8 + tc) * EPROJS + e] = a0 + a1;
}

__global__ __launch_bounds__(256) void k_comb(const float* __restrict__ part,
                                              float* __restrict__ out) {
  const int b = blockIdx.x >> 2, et = blockIdx.x & 3;
  const int e = et * 256 + threadIdx.x;
  float s = 0.f;
#pragma unroll
  for (int tc = 0; tc < 8; ++tc) s += part[((size_t)b * 8 + tc) * EPROJS + e];
  out[OFF_C + b * EPROJS + e] = s;
}

// ---------------------------------------------------------------------------
extern "C" void kernel_launch(void* const* d_in, const int* in_sizes, int n_in,
                              void* d_out, int out_size, void* d_ws, size_t ws_size,
                              hipStream_t stream) {
  const float* enc      = (const float*)d_in[0];
  const int*   lens     = (const int*)d_in[1];
  const float* dec_z    = (const float*)d_in[2];
  const float* att_prev = (const float*)d_in[3];
  const float* att_h    = (const float*)d_in[4];
  const float* att_c    = (const float*)d_in[5];
  const float* W_enc    = (const float*)d_in[6];
  const float* b_enc    = (const float*)d_in[7];
  const float* W_dec    = (const float*)d_in[8];
  const float* W_conv   = (const float*)d_in[9];
  const float* W_ih     = (const float*)d_in[10];
  const float* W_hh     = (const float*)d_in[11];
  const float* W_g      = (const float*)d_in[12];
  const float* b_g      = (const float*)d_in[13];
  float* out = (float*)d_out;
  float* ws  = (float*)d_ws;

  float* cf   = ws + WS_CF;
  float* v    = ws + WS_V;
  float* e_s  = ws + WS_E;
  float* wf   = ws + WS_WF;
  unsigned short* wt = (unsigned short*)(ws + WS_WT);
  float* part = ws + WS_PART;
  float* gp   = ws + WS_GP;
  float* dp   = ws + WS_DP;

  k_wprep     <<<512, 256, 0, stream>>>(W_enc, wt);
  k_conv      <<<BB * CH, 256, 0, stream>>>(att_prev, W_conv, cf);
  k_gates     <<<64, 256, 0, stream>>>(att_h, W_hh, gp);
  k_dec       <<<16, 256, 0, stream>>>(dec_z, W_dec, dp);
  k_lstm_v    <<<BB, 256, 0, stream>>>(gp, dp, cf, W_ih, att_c, v, out);
  k_score_mfma<<<BB * (TT_ALL / MT2), 512, 0, stream>>>(enc, wt, b_enc, W_g, b_g, v, lens, e_s);
  k_softmax   <<<BB, 256, 0, stream>>>(e_s, lens, wf, out);
  k_ctx       <<<BB * 32, 256, 0, stream>>>(enc, wf, lens, part);
  k_comb      <<<BB * 4, 256, 0, stream>>>(part, out);
}